// Round 5
// baseline (182.606 us; speedup 1.0000x reference)
//
#include <hip/hip_runtime.h>
#include <math.h>

// ---------------- workspace layout (float offsets) ----------------
#define OFF_W2P 0              // [64][224]  Wm2 pre-contracted with P
#define OFF_B2P 14336          // [224]
#define OFF_V   14560          // [20000][224]
#define WS_FLOATS 4494560

#define SC_Y0 0.0180421959121758f   // (1/sqrt(32))*(1/sqrt(96))
#define SC_Y2 0.015625f             // (1/sqrt(32))*(1/sqrt(128))
#define S2f 0.70710678118654752f
#define S6f 0.40824829046386302f
#define TWOS2f 1.41421356237309505f
#define TWOS6f 0.81649658092772603f
#define ISQRT3 0.57735026918962576f
#define ISQRT5 0.44721359549995794f
#define H0SC 0.08838834764831845f   // 1/sqrt(128)
#define H1SC 0.125f                 // 1/sqrt(64)
#define H2SC 0.17677669529663689f   // 1/sqrt(32)

__device__ __constant__ int KARR[7] = {0, 1, 2, 4, 5, 6, 8};

// ---------------- prep: Wm2p, bm2p, zero out ----------------
__global__ __launch_bounds__(256) void prep_kernel(
    const float* __restrict__ Wm2, const float* __restrict__ bm2,
    const float* __restrict__ P0, const float* __restrict__ P2,
    float* __restrict__ ws, float* __restrict__ out) {
  int j = blockIdx.x * 256 + threadIdx.x;
  if (j < 2304) out[j] = 0.f;

  if (j < 14336) {
    int s = j >> 11; int rem = j & 2047; int c = rem >> 5; int u = rem & 31;
    int k = KARR[s];
    const float* P;
    float sc;
    switch (s) {
      case 0: P = P0;      sc = SC_Y0; break;
      case 1: P = P2;      sc = SC_Y2; break;
      case 2: P = P0 + 32; sc = SC_Y0; break;
      case 3: P = P2 + 32; sc = SC_Y2; break;
      case 4: P = P2 + 64; sc = SC_Y2; break;
      case 5: P = P0 + 64; sc = SC_Y0; break;
      default: P = P2 + 96; sc = SC_Y2; break;
    }
    const float4* w4 = (const float4*)(Wm2 + c * 9216 + k * 1024 + u * 32);
    const float4* p4 = (const float4*)P;
    float acc = 0.f;
#pragma unroll
    for (int q = 0; q < 8; ++q) {
      float4 a = w4[q], b = p4[q];
      acc += a.x * b.x + a.y * b.y + a.z * b.z + a.w * b.w;
    }
    ws[OFF_W2P + c * 224 + s * 32 + u] = acc * sc;
  } else if (j < 14560) {
    int i = j - 14336; int s = i >> 5; int u = i & 31; int k = KARR[s];
    const float* P;
    float sc;
    switch (s) {
      case 0: P = P0;      sc = SC_Y0; break;
      case 1: P = P2;      sc = SC_Y2; break;
      case 2: P = P0 + 32; sc = SC_Y0; break;
      case 3: P = P2 + 32; sc = SC_Y2; break;
      case 4: P = P2 + 64; sc = SC_Y2; break;
      case 5: P = P0 + 64; sc = SC_Y0; break;
      default: P = P2 + 96; sc = SC_Y2; break;
    }
    const float* b = bm2 + k * 1024 + u * 32;
    float acc = 0.f;
#pragma unroll
    for (int w = 0; w < 32; ++w) acc += b[w] * P[w];
    ws[OFF_B2P + s * 32 + u] = acc * sc;
  }
}

// ---------------- kv: V[n][o] = silu(x@Wm1+b) @ W2p + b2p, 16 nodes/block ----------------
// LDS: xs[16][132] (8448 B) + hiT[64][19] (4864 B) = 13312 B -> high occupancy
__global__ __launch_bounds__(256) void kv_kernel(
    const float* __restrict__ xs_g, const float* __restrict__ Wm1,
    const float* __restrict__ bm1, float* __restrict__ ws) {
  __shared__ __align__(16) float xs[16][132];
  __shared__ float hiT[64][19];
  const int tid = threadIdx.x;
  const int n0 = blockIdx.x * 16;   // 1250 * 16 == 20000

  for (int idx = tid; idx < 512; idx += 256) {
    const int row = idx >> 5, c4 = idx & 31;
    *(float4*)&xs[row][c4 * 4] = *(const float4*)(xs_g + (n0 + row) * 128 + c4 * 4);
  }
  __syncthreads();

  {  // hidden: 1n x 4c per thread, 256 threads cover 16n x 64c
    const int n = tid >> 4, c0 = (tid & 15) * 4;
    float acc[4] = {0.f, 0.f, 0.f, 0.f};
#pragma unroll 4
    for (int mq = 0; mq < 32; ++mq) {
      const float4 xv = *(float4*)&xs[n][mq * 4];
      const float xa[4] = {xv.x, xv.y, xv.z, xv.w};
#pragma unroll
      for (int r = 0; r < 4; ++r) {
        const float4 w = *(const float4*)(Wm1 + (mq * 4 + r) * 64 + c0);
        acc[0] += xa[r] * w.x; acc[1] += xa[r] * w.y;
        acc[2] += xa[r] * w.z; acc[3] += xa[r] * w.w;
      }
    }
    const float4 bb = *(const float4*)(bm1 + c0);
    const float bv[4] = {bb.x, bb.y, bb.z, bb.w};
#pragma unroll
    for (int jj = 0; jj < 4; ++jj) {
      float z = acc[jj] + bv[jj];
      hiT[c0 + jj][n] = z / (1.f + __expf(-z));
    }
  }
  __syncthreads();

  if (tid < 224) {  // V: 2n x 8o per thread -> ws
    const int og = tid >> 3, ng = tid & 7;
    const int o0 = og * 8, n = ng * 2;
    const float4 blo = *(const float4*)(ws + OFF_B2P + o0);
    const float4 bhi = *(const float4*)(ws + OFF_B2P + o0 + 4);
    float acc[2][8];
#pragma unroll
    for (int i = 0; i < 2; ++i) {
      acc[i][0] = blo.x; acc[i][1] = blo.y; acc[i][2] = blo.z; acc[i][3] = blo.w;
      acc[i][4] = bhi.x; acc[i][5] = bhi.y; acc[i][6] = bhi.z; acc[i][7] = bhi.w;
    }
#pragma unroll 2
    for (int c = 0; c < 64; ++c) {
      const float h0v = hiT[c][n], h1v = hiT[c][n + 1];
      const float4 wlo = *(const float4*)(ws + OFF_W2P + c * 224 + o0);
      const float4 whi = *(const float4*)(ws + OFF_W2P + c * 224 + o0 + 4);
      const float wv[8] = {wlo.x, wlo.y, wlo.z, wlo.w, whi.x, whi.y, whi.z, whi.w};
#pragma unroll
      for (int jj = 0; jj < 8; ++jj) {
        acc[0][jj] += h0v * wv[jj];
        acc[1][jj] += h1v * wv[jj];
      }
    }
#pragma unroll
    for (int i = 0; i < 2; ++i) {
      const int n_g = n0 + n + i;
      float4 a = {acc[i][0], acc[i][1], acc[i][2], acc[i][3]};
      float4 b = {acc[i][4], acc[i][5], acc[i][6], acc[i][7]};
      *(float4*)(ws + OFF_V + n_g * 224 + o0) = a;
      *(float4*)(ws + OFF_V + n_g * 224 + o0 + 4) = b;
    }
  }
}

// ---------------- khd: h-projections (global x) + path math + atomics ----------------
// LDS (bytes): Vs[16][224] @0 (14336), h0s[16][32] @14336 (2048),
//   h1s[16][3][32] @16384 (6144), h2s[16][5][32] @22528 (10240),
//   sphs[16][6] @32768 (384), batch_s[16] @33152 (64) -> 33216 B, 4 blocks/CU
__global__ __launch_bounds__(256) void khd_kernel(
    const float* __restrict__ xsph, const int* __restrict__ batch,
    const float* __restrict__ W0e, const float* __restrict__ W1o,
    const float* __restrict__ W2e,
    const float* __restrict__ ws, float* __restrict__ out, const float norm2) {
  __shared__ __align__(16) char smem[33216];
  float (*Vs)[224]     = (float (*)[224])smem;
  float (*h0s)[32]     = (float (*)[32])(smem + 14336);
  float (*h1s)[3][32]  = (float (*)[3][32])(smem + 16384);
  float (*h2s)[5][32]  = (float (*)[5][32])(smem + 22528);
  float (*sphs)[6]     = (float (*)[6])(smem + 32768);
  int* batch_s         = (int*)(smem + 33152);

  const int tid = threadIdx.x;
  const int n0 = blockIdx.x * 16;   // 1250 * 16 == 20000

  if (tid < 16) batch_s[tid] = batch[n0 + tid];

  // ---- phase A: wave-split work. tid<64: h0 | <128: h1 | <192: h2 | <256: V prefetch ----
  if (tid < 64) {
    const int n = tid & 15, ug = tid >> 4, u0 = ug * 8;
    const float4* x4 = (const float4*)(xsph + (size_t)(n0 + n) * 480);
    float acc[8] = {0.f, 0.f, 0.f, 0.f, 0.f, 0.f, 0.f, 0.f};
#pragma unroll 4
    for (int mq = 0; mq < 32; ++mq) {
      const float4 xv = x4[mq];
      const float xa[4] = {xv.x, xv.y, xv.z, xv.w};
#pragma unroll
      for (int r = 0; r < 4; ++r) {
        const float4 wl = *(const float4*)(W0e + (mq * 4 + r) * 32 + u0);
        const float4 wh = *(const float4*)(W0e + (mq * 4 + r) * 32 + u0 + 4);
        const float xr = xa[r];
        acc[0] += xr * wl.x; acc[1] += xr * wl.y; acc[2] += xr * wl.z; acc[3] += xr * wl.w;
        acc[4] += xr * wh.x; acc[5] += xr * wh.y; acc[6] += xr * wh.z; acc[7] += xr * wh.w;
      }
    }
    float4 a = {acc[0] * H0SC, acc[1] * H0SC, acc[2] * H0SC, acc[3] * H0SC};
    float4 b = {acc[4] * H0SC, acc[5] * H0SC, acc[6] * H0SC, acc[7] * H0SC};
    *(float4*)&h0s[n][u0] = a;
    *(float4*)&h0s[n][u0 + 4] = b;
  } else if (tid < 128) {
    const int t = tid - 64;
    const int n = t & 15, ug = t >> 4, u0 = ug * 8;
    const float4* x4 = (const float4*)(xsph + (size_t)(n0 + n) * 480);
    float acc[3][8] = {{0.f}};
#pragma unroll 2
    for (int mq = 0; mq < 16; ++mq) {
      const float4 a0 = x4[32 + mq * 3];
      const float4 a1 = x4[32 + mq * 3 + 1];
      const float4 a2 = x4[32 + mq * 3 + 2];
      const float xa[12] = {a0.x, a0.y, a0.z, a0.w, a1.x, a1.y, a1.z, a1.w,
                            a2.x, a2.y, a2.z, a2.w};
#pragma unroll
      for (int mm = 0; mm < 4; ++mm) {
        const float4 wl = *(const float4*)(W1o + (mq * 4 + mm) * 32 + u0);
        const float4 wh = *(const float4*)(W1o + (mq * 4 + mm) * 32 + u0 + 4);
        const float wv[8] = {wl.x, wl.y, wl.z, wl.w, wh.x, wh.y, wh.z, wh.w};
#pragma unroll
        for (int j = 0; j < 3; ++j) {
          const float xr = xa[mm * 3 + j];
#pragma unroll
          for (int jj = 0; jj < 8; ++jj) acc[j][jj] += xr * wv[jj];
        }
      }
    }
#pragma unroll
    for (int j = 0; j < 3; ++j) {
      float4 a = {acc[j][0] * H1SC, acc[j][1] * H1SC, acc[j][2] * H1SC, acc[j][3] * H1SC};
      float4 b = {acc[j][4] * H1SC, acc[j][5] * H1SC, acc[j][6] * H1SC, acc[j][7] * H1SC};
      *(float4*)&h1s[n][j][u0] = a;
      *(float4*)&h1s[n][j][u0 + 4] = b;
    }
  } else if (tid < 192) {
    const int t = tid - 128;
    const int n = t & 15, ug = t >> 4, u0 = ug * 8;
    const float4* x4 = (const float4*)(xsph + (size_t)(n0 + n) * 480);
    float acc[5][8] = {{0.f}};
#pragma unroll 2
    for (int mq = 0; mq < 8; ++mq) {
      const float4 a0 = x4[80 + mq * 5];
      const float4 a1 = x4[80 + mq * 5 + 1];
      const float4 a2 = x4[80 + mq * 5 + 2];
      const float4 a3 = x4[80 + mq * 5 + 3];
      const float4 a4 = x4[80 + mq * 5 + 4];
      const float xa[20] = {a0.x, a0.y, a0.z, a0.w, a1.x, a1.y, a1.z, a1.w,
                            a2.x, a2.y, a2.z, a2.w, a3.x, a3.y, a3.z, a3.w,
                            a4.x, a4.y, a4.z, a4.w};
#pragma unroll
      for (int mm = 0; mm < 4; ++mm) {
        const float4 wl = *(const float4*)(W2e + (mq * 4 + mm) * 32 + u0);
        const float4 wh = *(const float4*)(W2e + (mq * 4 + mm) * 32 + u0 + 4);
        const float wv[8] = {wl.x, wl.y, wl.z, wl.w, wh.x, wh.y, wh.z, wh.w};
#pragma unroll
        for (int j = 0; j < 5; ++j) {
          const float xr = xa[mm * 5 + j];
#pragma unroll
          for (int jj = 0; jj < 8; ++jj) acc[j][jj] += xr * wv[jj];
        }
      }
    }
#pragma unroll
    for (int j = 0; j < 5; ++j) {
      float4 a = {acc[j][0] * H2SC, acc[j][1] * H2SC, acc[j][2] * H2SC, acc[j][3] * H2SC};
      float4 b = {acc[j][4] * H2SC, acc[j][5] * H2SC, acc[j][6] * H2SC, acc[j][7] * H2SC};
      *(float4*)&h2s[n][j][u0] = a;
      *(float4*)&h2s[n][j][u0 + 4] = b;
    }
  } else {
    const int t = tid - 192;
    const float* Vg = ws + OFF_V + (size_t)n0 * 224;
#pragma unroll
    for (int q = 0; q < 14; ++q) {
      const int idx = t + q * 64;           // 896 float4 total
      const int n = idx / 56, o4 = idx % 56;
      *(float4*)&Vs[n][o4 * 4] = *(const float4*)(Vg + n * 224 + o4 * 4);
    }
  }
  __syncthreads();

  // ---- phase B: per-(n,u) path math, 2 halves of 8 nodes ----
  {
    const int nl = tid >> 5, u = tid & 31;
#pragma unroll 2
    for (int half = 0; half < 2; ++half) {
      const int n = half * 8 + nl;
      const float h0 = h0s[n][u];
      const float h1a = h1s[n][0][u], h1b = h1s[n][1][u], h1c = h1s[n][2][u];
      float h2v[5];
#pragma unroll
      for (int j = 0; j < 5; ++j) h2v[j] = h2s[n][j][u];
      const float v0 = Vs[n][u],       v1 = Vs[n][u + 32],
                  v2 = Vs[n][u + 64],  v3 = Vs[n][u + 96],
                  v4 = Vs[n][u + 128], v5 = Vs[n][u + 160],
                  v6 = Vs[n][u + 192];

      const float d11 = h1a * h1a + h1b * h1b + h1c * h1c;
      const float d22 = h2v[0] * h2v[0] + h2v[1] * h2v[1] + h2v[2] * h2v[2] +
                        h2v[3] * h2v[3] + h2v[4] * h2v[4];
      float y0 = v0 * h0 * h0 + v2 * d11 * ISQRT3 + v5 * d22 * ISQRT5;

      const float o00 = h1a * h1a, o01 = h1a * h1b, o02 = h1a * h1c;
      const float o11 = h1b * h1b, o12 = h1b * h1c, o22 = h1c * h1c;
      const float t40 = TWOS2f * o01, t41 = TWOS2f * o12;
      const float t42 = S6f * (2.f * o22 - o00 - o11);
      const float t43 = TWOS2f * o02, t44 = S2f * (o00 - o11);

      const float A00 = -S6f * h2v[2] + S2f * h2v[4];
      const float A01 = S2f * h2v[0];
      const float A02 = S2f * h2v[3];
      const float A11 = -S6f * h2v[2] - S2f * h2v[4];
      const float A12 = S2f * h2v[1];
      const float A22 = TWOS6f * h2v[2];
      const float B00 = A00 * A00 + A01 * A01 + A02 * A02;
      const float B01 = A00 * A01 + A01 * A11 + A02 * A12;
      const float B02 = A00 * A02 + A01 * A12 + A02 * A22;
      const float B11 = A01 * A01 + A11 * A11 + A12 * A12;
      const float B12 = A01 * A02 + A11 * A12 + A12 * A22;
      const float B22 = A02 * A02 + A12 * A12 + A22 * A22;
      const float t80 = TWOS2f * B01, t81 = TWOS2f * B12;
      const float t82 = S6f * (2.f * B22 - B00 - B11);
      const float t83 = TWOS2f * B02, t84 = S2f * (B00 - B11);

      const float w15 = (v1 + v4) * h0;
      const float v6n = v6 * norm2;
      float y2r[5];
      y2r[0] = w15 * h2v[0] + v3 * t40 + v6n * t80;
      y2r[1] = w15 * h2v[1] + v3 * t41 + v6n * t81;
      y2r[2] = w15 * h2v[2] + v3 * t42 + v6n * t82;
      y2r[3] = w15 * h2v[3] + v3 * t43 + v6n * t83;
      y2r[4] = w15 * h2v[4] + v3 * t44 + v6n * t84;

#pragma unroll
      for (int off = 16; off > 0; off >>= 1) {
        y0 += __shfl_xor(y0, off, 32);
#pragma unroll
        for (int r = 0; r < 5; ++r) y2r[r] += __shfl_xor(y2r[r], off, 32);
      }
      if (u == 0) {
        sphs[n][0] = y0;
#pragma unroll
        for (int r = 0; r < 5; ++r) sphs[n][1 + r] = y2r[r];
      }
    }
  }
  __syncthreads();

  // ---- phase C: cart + segment-merged atomics ----
  if (tid < 9) {
    const float QW[9][6] = {
        {ISQRT3, 0.f, 0.f, -S6f, 0.f, S2f},
        {0.f, S2f, 0.f, 0.f, 0.f, 0.f},
        {0.f, 0.f, 0.f, 0.f, S2f, 0.f},
        {0.f, S2f, 0.f, 0.f, 0.f, 0.f},
        {ISQRT3, 0.f, 0.f, -S6f, 0.f, -S2f},
        {0.f, 0.f, S2f, 0.f, 0.f, 0.f},
        {0.f, 0.f, 0.f, 0.f, S2f, 0.f},
        {0.f, 0.f, S2f, 0.f, 0.f, 0.f},
        {ISQRT3, 0.f, 0.f, TWOS6f, 0.f, 0.f}};
    const int a = tid / 3, b = tid % 3;
    const int rolled = ((a + 1) % 3) * 3 + ((b + 1) % 3);
    const float c0 = QW[tid][0], c1 = QW[tid][1], c2 = QW[tid][2];
    const float c3 = QW[tid][3], c4 = QW[tid][4], c5 = QW[tid][5];
    int cur_g = batch_s[0];
    float acc = 0.f;
#pragma unroll 4
    for (int q = 0; q < 16; ++q) {
      const int g = batch_s[q];
      const float val = c0 * sphs[q][0] + c1 * sphs[q][1] + c2 * sphs[q][2] +
                        c3 * sphs[q][3] + c4 * sphs[q][4] + c5 * sphs[q][5];
      if (g != cur_g) {
        atomicAdd(out + cur_g * 9 + rolled, acc);
        acc = 0.f;
        cur_g = g;
      }
      acc += val;
    }
    atomicAdd(out + cur_g * 9 + rolled, acc);
  }
}

extern "C" void kernel_launch(void* const* d_in, const int* in_sizes, int n_in,
                              void* d_out, int out_size, void* d_ws, size_t ws_size,
                              hipStream_t stream) {
  const float* x_scalar = (const float*)d_in[0];
  const float* x_sph    = (const float*)d_in[1];
  const int*   batch    = (const int*)d_in[2];
  const float* W0e      = (const float*)d_in[3];
  const float* W1o      = (const float*)d_in[4];
  const float* W2e      = (const float*)d_in[5];
  const float* Wm1      = (const float*)d_in[6];
  const float* bm1      = (const float*)d_in[7];
  const float* Wm2      = (const float*)d_in[8];
  const float* bm2      = (const float*)d_in[9];
  const float* P0       = (const float*)d_in[10];
  // P1 (d_in[11]) provably unused: C111/C221 antisymmetric vs h(x)h of same h.
  const float* P2       = (const float*)d_in[12];
  float* ws  = (float*)d_ws;
  float* out = (float*)d_out;

  if (ws_size < (size_t)WS_FLOATS * sizeof(float)) return;

  // host-side C222 normalization (pure CPU double math; = sqrt(12/7))
  double Q2[5][3][3] = {};
  const double s2d = 0.70710678118654752440, s6d = 0.40824829046386301637;
  Q2[0][0][1] = Q2[0][1][0] = s2d;
  Q2[1][1][2] = Q2[1][2][1] = s2d;
  Q2[2][0][0] = Q2[2][1][1] = -s6d; Q2[2][2][2] = 2.0 * s6d;
  Q2[3][0][2] = Q2[3][2][0] = s2d;
  Q2[4][0][0] = s2d; Q2[4][1][1] = -s2d;
  double ss = 0.0;
  for (int i = 0; i < 5; ++i)
    for (int jj = 0; jj < 5; ++jj) {
      double S[3][3];
      for (int a = 0; a < 3; ++a)
        for (int d = 0; d < 3; ++d) {
          double m1 = 0, m2 = 0;
          for (int b = 0; b < 3; ++b) {
            m1 += Q2[i][a][b] * Q2[jj][d][b];
            m2 += Q2[i][d][b] * Q2[jj][a][b];
          }
          S[a][d] = 0.5 * (m1 + m2);
        }
      double tr = (S[0][0] + S[1][1] + S[2][2]) / 3.0;
      S[0][0] -= tr; S[1][1] -= tr; S[2][2] -= tr;
      for (int kk = 0; kk < 5; ++kk) {
        double cc = 0;
        for (int a = 0; a < 3; ++a)
          for (int d = 0; d < 3; ++d) cc += Q2[kk][a][d] * S[a][d];
        ss += cc * cc;
      }
    }
  const float norm2 = (float)sqrt(5.0 / ss);

  prep_kernel<<<57, 256, 0, stream>>>(Wm2, bm2, P0, P2, ws, out);
  kv_kernel<<<1250, 256, 0, stream>>>(x_scalar, Wm1, bm1, ws);
  khd_kernel<<<1250, 256, 0, stream>>>(x_sph, batch, W0e, W1o, W2e, ws, out, norm2);
}

// Round 6
// 173.168 us; speedup vs baseline: 1.0545x; 1.0545x over previous
//
#include <hip/hip_runtime.h>
#include <math.h>

// ---------------- workspace layout (float offsets) ----------------
#define OFF_W2P 0              // [64][224]  Wm2 pre-contracted with P
#define OFF_B2P 14336          // [224]
#define OFF_V   14560          // [20000][224]
#define WS_FLOATS 4494560

#define SC_Y0 0.0180421959121758f   // (1/sqrt(32))*(1/sqrt(96))
#define SC_Y2 0.015625f             // (1/sqrt(32))*(1/sqrt(128))
#define S2f 0.70710678118654752f
#define S6f 0.40824829046386302f
#define TWOS2f 1.41421356237309505f
#define TWOS6f 0.81649658092772603f
#define ISQRT3 0.57735026918962576f
#define ISQRT5 0.44721359549995794f
#define H0SC 0.08838834764831845f   // 1/sqrt(128)
#define H1SC 0.125f                 // 1/sqrt(64)
#define H2SC 0.17677669529663689f   // 1/sqrt(32)

__device__ __constant__ int KARR[7] = {0, 1, 2, 4, 5, 6, 8};

// ---------------- prep: Wm2p, bm2p, zero out ----------------
__global__ __launch_bounds__(256) void prep_kernel(
    const float* __restrict__ Wm2, const float* __restrict__ bm2,
    const float* __restrict__ P0, const float* __restrict__ P2,
    float* __restrict__ ws, float* __restrict__ out) {
  int j = blockIdx.x * 256 + threadIdx.x;
  if (j < 2304) out[j] = 0.f;

  if (j < 14336) {
    int s = j >> 11; int rem = j & 2047; int c = rem >> 5; int u = rem & 31;
    int k = KARR[s];
    const float* P;
    float sc;
    switch (s) {
      case 0: P = P0;      sc = SC_Y0; break;
      case 1: P = P2;      sc = SC_Y2; break;
      case 2: P = P0 + 32; sc = SC_Y0; break;
      case 3: P = P2 + 32; sc = SC_Y2; break;
      case 4: P = P2 + 64; sc = SC_Y2; break;
      case 5: P = P0 + 64; sc = SC_Y0; break;
      default: P = P2 + 96; sc = SC_Y2; break;
    }
    const float4* w4 = (const float4*)(Wm2 + c * 9216 + k * 1024 + u * 32);
    const float4* p4 = (const float4*)P;
    float acc = 0.f;
#pragma unroll
    for (int q = 0; q < 8; ++q) {
      float4 a = w4[q], b = p4[q];
      acc += a.x * b.x + a.y * b.y + a.z * b.z + a.w * b.w;
    }
    ws[OFF_W2P + c * 224 + s * 32 + u] = acc * sc;
  } else if (j < 14560) {
    int i = j - 14336; int s = i >> 5; int u = i & 31; int k = KARR[s];
    const float* P;
    float sc;
    switch (s) {
      case 0: P = P0;      sc = SC_Y0; break;
      case 1: P = P2;      sc = SC_Y2; break;
      case 2: P = P0 + 32; sc = SC_Y0; break;
      case 3: P = P2 + 32; sc = SC_Y2; break;
      case 4: P = P2 + 64; sc = SC_Y2; break;
      case 5: P = P0 + 64; sc = SC_Y0; break;
      default: P = P2 + 96; sc = SC_Y2; break;
    }
    const float* b = bm2 + k * 1024 + u * 32;
    float acc = 0.f;
#pragma unroll
    for (int w = 0; w < 32; ++w) acc += b[w] * P[w];
    ws[OFF_B2P + s * 32 + u] = acc * sc;
  }
}

// ---------------- kv: V[n][o] = silu(x@Wm1+b) @ W2p + b2p, 16 nodes/block ----------------
__global__ __launch_bounds__(256) void kv_kernel(
    const float* __restrict__ xs_g, const float* __restrict__ Wm1,
    const float* __restrict__ bm1, float* __restrict__ ws) {
  __shared__ __align__(16) float xs[16][132];
  __shared__ float hiT[64][19];
  const int tid = threadIdx.x;
  const int n0 = blockIdx.x * 16;   // 1250 * 16 == 20000

  for (int idx = tid; idx < 512; idx += 256) {
    const int row = idx >> 5, c4 = idx & 31;
    *(float4*)&xs[row][c4 * 4] = *(const float4*)(xs_g + (n0 + row) * 128 + c4 * 4);
  }
  __syncthreads();

  {  // hidden: 1n x 4c per thread
    const int n = tid >> 4, c0 = (tid & 15) * 4;
    float acc[4] = {0.f, 0.f, 0.f, 0.f};
#pragma unroll 4
    for (int mq = 0; mq < 32; ++mq) {
      const float4 xv = *(float4*)&xs[n][mq * 4];
      const float xa[4] = {xv.x, xv.y, xv.z, xv.w};
#pragma unroll
      for (int r = 0; r < 4; ++r) {
        const float4 w = *(const float4*)(Wm1 + (mq * 4 + r) * 64 + c0);
        acc[0] += xa[r] * w.x; acc[1] += xa[r] * w.y;
        acc[2] += xa[r] * w.z; acc[3] += xa[r] * w.w;
      }
    }
    const float4 bb = *(const float4*)(bm1 + c0);
    const float bv[4] = {bb.x, bb.y, bb.z, bb.w};
#pragma unroll
    for (int jj = 0; jj < 4; ++jj) {
      float z = acc[jj] + bv[jj];
      hiT[c0 + jj][n] = z / (1.f + __expf(-z));
    }
  }
  __syncthreads();

  if (tid < 224) {  // V: 2n x 8o per thread -> ws
    const int og = tid >> 3, ng = tid & 7;
    const int o0 = og * 8, n = ng * 2;
    const float4 blo = *(const float4*)(ws + OFF_B2P + o0);
    const float4 bhi = *(const float4*)(ws + OFF_B2P + o0 + 4);
    float acc[2][8];
#pragma unroll
    for (int i = 0; i < 2; ++i) {
      acc[i][0] = blo.x; acc[i][1] = blo.y; acc[i][2] = blo.z; acc[i][3] = blo.w;
      acc[i][4] = bhi.x; acc[i][5] = bhi.y; acc[i][6] = bhi.z; acc[i][7] = bhi.w;
    }
#pragma unroll 2
    for (int c = 0; c < 64; ++c) {
      const float h0v = hiT[c][n], h1v = hiT[c][n + 1];
      const float4 wlo = *(const float4*)(ws + OFF_W2P + c * 224 + o0);
      const float4 whi = *(const float4*)(ws + OFF_W2P + c * 224 + o0 + 4);
      const float wv[8] = {wlo.x, wlo.y, wlo.z, wlo.w, whi.x, whi.y, whi.z, whi.w};
#pragma unroll
      for (int jj = 0; jj < 8; ++jj) {
        acc[0][jj] += h0v * wv[jj];
        acc[1][jj] += h1v * wv[jj];
      }
    }
#pragma unroll
    for (int i = 0; i < 2; ++i) {
      const int n_g = n0 + n + i;
      float4 a = {acc[i][0], acc[i][1], acc[i][2], acc[i][3]};
      float4 b = {acc[i][4], acc[i][5], acc[i][6], acc[i][7]};
      *(float4*)(ws + OFF_V + n_g * 224 + o0) = a;
      *(float4*)(ws + OFF_V + n_g * 224 + o0 + 4) = b;
    }
  }
}

// ---------------- khd: 8 nodes/block, LDS-staged x_sph, register-resident V ----------------
// LDS (bytes): xp[8][484] @0 (15488), h0s[8][36] @15488 (1152),
//   h1s[8][3][36] @16640 (3456), h2s[8][5][36] @20096 (5760),
//   sphs[8][6] @25856 (192), batch_s[8] @26048 (32) -> 26080 B, 6 blocks/CU
__global__ __launch_bounds__(256) void khd_kernel(
    const float* __restrict__ xsph, const int* __restrict__ batch,
    const float* __restrict__ W0e, const float* __restrict__ W1o,
    const float* __restrict__ W2e,
    const float* __restrict__ ws, float* __restrict__ out, const float norm2) {
  __shared__ __align__(16) char smem[26080];
  float (*xp)[484]    = (float (*)[484])smem;
  float (*h0s)[36]    = (float (*)[36])(smem + 15488);
  float (*h1s)[3][36] = (float (*)[3][36])(smem + 16640);
  float (*h2s)[5][36] = (float (*)[5][36])(smem + 20096);
  float (*sphs)[6]    = (float (*)[6])(smem + 25856);
  int* batch_s        = (int*)(smem + 26048);

  const int tid = threadIdx.x;
  const int n0 = blockIdx.x * 8;   // 2500 * 8 == 20000

  // ---- V into registers immediately (coalesced: 32 consecutive u per half-wave) ----
  const int nl = tid >> 5, u = tid & 31;
  const float* Vg = ws + OFF_V + (size_t)(n0 + nl) * 224 + u;
  const float v0 = Vg[0],   v1 = Vg[32],  v2 = Vg[64],  v3 = Vg[96];
  const float v4 = Vg[128], v5 = Vg[160], v6 = Vg[192];

  if (tid < 8) batch_s[tid] = batch[n0 + tid];

  // ---- phase 0: stage x_sph tile coalesced (960 float4) ----
  for (int idx = tid; idx < 960; idx += 256) {
    const int row = idx / 120, c4 = idx % 120;
    *(float4*)&xp[row][c4 * 4] =
        *(const float4*)(xsph + (size_t)(n0 + row) * 480 + c4 * 4);
  }
  __syncthreads();

  // ---- phase A: wave-split h-projections from LDS (all conflict-free) ----
  if (tid < 64) {
    // wave 0: h1, j = 0,1
    const int n = tid & 7, u0 = ((tid >> 3) & 7) * 4;
    float acc[2][4] = {{0.f}};
#pragma unroll 2
    for (int mq = 0; mq < 16; ++mq) {
      const float4 a0 = *(float4*)&xp[n][128 + mq * 12];
      const float4 a1 = *(float4*)&xp[n][128 + mq * 12 + 4];
      const float4 a2 = *(float4*)&xp[n][128 + mq * 12 + 8];
      const float xa[12] = {a0.x, a0.y, a0.z, a0.w, a1.x, a1.y, a1.z, a1.w,
                            a2.x, a2.y, a2.z, a2.w};
#pragma unroll
      for (int mm = 0; mm < 4; ++mm) {
        const float4 w = *(const float4*)(W1o + (mq * 4 + mm) * 32 + u0);
        const float wv[4] = {w.x, w.y, w.z, w.w};
#pragma unroll
        for (int j = 0; j < 2; ++j) {
          const float xr = xa[mm * 3 + j];
#pragma unroll
          for (int jj = 0; jj < 4; ++jj) acc[j][jj] += xr * wv[jj];
        }
      }
    }
#pragma unroll
    for (int j = 0; j < 2; ++j) {
      float4 a = {acc[j][0] * H1SC, acc[j][1] * H1SC, acc[j][2] * H1SC, acc[j][3] * H1SC};
      *(float4*)&h1s[n][j][u0] = a;
    }
  } else if (tid < 128) {
    // wave 1: h2, j = 1..4
    const int t = tid - 64;
    const int n = t & 7, u0 = ((t >> 3) & 7) * 4;
    float acc[4][4] = {{0.f}};
#pragma unroll 2
    for (int mq = 0; mq < 8; ++mq) {
      const float4 a0 = *(float4*)&xp[n][320 + mq * 20];
      const float4 a1 = *(float4*)&xp[n][320 + mq * 20 + 4];
      const float4 a2 = *(float4*)&xp[n][320 + mq * 20 + 8];
      const float4 a3 = *(float4*)&xp[n][320 + mq * 20 + 12];
      const float4 a4 = *(float4*)&xp[n][320 + mq * 20 + 16];
      const float xa[20] = {a0.x, a0.y, a0.z, a0.w, a1.x, a1.y, a1.z, a1.w,
                            a2.x, a2.y, a2.z, a2.w, a3.x, a3.y, a3.z, a3.w,
                            a4.x, a4.y, a4.z, a4.w};
#pragma unroll
      for (int mm = 0; mm < 4; ++mm) {
        const float4 w = *(const float4*)(W2e + (mq * 4 + mm) * 32 + u0);
        const float wv[4] = {w.x, w.y, w.z, w.w};
#pragma unroll
        for (int j = 1; j < 5; ++j) {
          const float xr = xa[mm * 5 + j];
#pragma unroll
          for (int jj = 0; jj < 4; ++jj) acc[j - 1][jj] += xr * wv[jj];
        }
      }
    }
#pragma unroll
    for (int j = 1; j < 5; ++j) {
      float4 a = {acc[j - 1][0] * H2SC, acc[j - 1][1] * H2SC,
                  acc[j - 1][2] * H2SC, acc[j - 1][3] * H2SC};
      *(float4*)&h2s[n][j][u0] = a;
    }
  } else if (tid < 192) {
    // wave 2: h0
    const int t = tid - 128;
    const int n = t & 7, u0 = ((t >> 3) & 7) * 4;
    float acc[4] = {0.f, 0.f, 0.f, 0.f};
#pragma unroll 4
    for (int mq = 0; mq < 32; ++mq) {
      const float4 xv = *(float4*)&xp[n][mq * 4];
      const float xa[4] = {xv.x, xv.y, xv.z, xv.w};
#pragma unroll
      for (int r = 0; r < 4; ++r) {
        const float4 w = *(const float4*)(W0e + (mq * 4 + r) * 32 + u0);
        acc[0] += xa[r] * w.x; acc[1] += xa[r] * w.y;
        acc[2] += xa[r] * w.z; acc[3] += xa[r] * w.w;
      }
    }
    float4 a = {acc[0] * H0SC, acc[1] * H0SC, acc[2] * H0SC, acc[3] * H0SC};
    *(float4*)&h0s[n][u0] = a;
  } else {
    // wave 3: h1 j=2 and h2 j=0
    const int t = tid - 192;
    const int n = t & 7, u0 = ((t >> 3) & 7) * 4;
    float acc1[4] = {0.f, 0.f, 0.f, 0.f};
#pragma unroll 2
    for (int mq = 0; mq < 16; ++mq) {
      const float4 a0 = *(float4*)&xp[n][128 + mq * 12];
      const float4 a1 = *(float4*)&xp[n][128 + mq * 12 + 4];
      const float4 a2 = *(float4*)&xp[n][128 + mq * 12 + 8];
      const float xa[12] = {a0.x, a0.y, a0.z, a0.w, a1.x, a1.y, a1.z, a1.w,
                            a2.x, a2.y, a2.z, a2.w};
#pragma unroll
      for (int mm = 0; mm < 4; ++mm) {
        const float4 w = *(const float4*)(W1o + (mq * 4 + mm) * 32 + u0);
        const float xr = xa[mm * 3 + 2];
        acc1[0] += xr * w.x; acc1[1] += xr * w.y;
        acc1[2] += xr * w.z; acc1[3] += xr * w.w;
      }
    }
    {
      float4 a = {acc1[0] * H1SC, acc1[1] * H1SC, acc1[2] * H1SC, acc1[3] * H1SC};
      *(float4*)&h1s[n][2][u0] = a;
    }
    float acc2[4] = {0.f, 0.f, 0.f, 0.f};
#pragma unroll 2
    for (int mq = 0; mq < 8; ++mq) {
      const float4 a0 = *(float4*)&xp[n][320 + mq * 20];
      const float4 a1 = *(float4*)&xp[n][320 + mq * 20 + 4];
      const float4 a2 = *(float4*)&xp[n][320 + mq * 20 + 8];
      const float4 a3 = *(float4*)&xp[n][320 + mq * 20 + 12];
      const float4 a4 = *(float4*)&xp[n][320 + mq * 20 + 16];
      const float xa[20] = {a0.x, a0.y, a0.z, a0.w, a1.x, a1.y, a1.z, a1.w,
                            a2.x, a2.y, a2.z, a2.w, a3.x, a3.y, a3.z, a3.w,
                            a4.x, a4.y, a4.z, a4.w};
#pragma unroll
      for (int mm = 0; mm < 4; ++mm) {
        const float4 w = *(const float4*)(W2e + (mq * 4 + mm) * 32 + u0);
        const float xr = xa[mm * 5 + 0];
        acc2[0] += xr * w.x; acc2[1] += xr * w.y;
        acc2[2] += xr * w.z; acc2[3] += xr * w.w;
      }
    }
    {
      float4 a = {acc2[0] * H2SC, acc2[1] * H2SC, acc2[2] * H2SC, acc2[3] * H2SC};
      *(float4*)&h2s[n][0][u0] = a;
    }
  }
  __syncthreads();

  // ---- phase B: per-(n,u) path math (h from LDS, V in registers) ----
  {
    const float h0 = h0s[nl][u];
    const float h1a = h1s[nl][0][u], h1b = h1s[nl][1][u], h1c = h1s[nl][2][u];
    float h2v[5];
#pragma unroll
    for (int j = 0; j < 5; ++j) h2v[j] = h2s[nl][j][u];

    const float d11 = h1a * h1a + h1b * h1b + h1c * h1c;
    const float d22 = h2v[0] * h2v[0] + h2v[1] * h2v[1] + h2v[2] * h2v[2] +
                      h2v[3] * h2v[3] + h2v[4] * h2v[4];
    float y0 = v0 * h0 * h0 + v2 * d11 * ISQRT3 + v5 * d22 * ISQRT5;

    const float o00 = h1a * h1a, o01 = h1a * h1b, o02 = h1a * h1c;
    const float o11 = h1b * h1b, o12 = h1b * h1c, o22 = h1c * h1c;
    const float t40 = TWOS2f * o01, t41 = TWOS2f * o12;
    const float t42 = S6f * (2.f * o22 - o00 - o11);
    const float t43 = TWOS2f * o02, t44 = S2f * (o00 - o11);

    const float A00 = -S6f * h2v[2] + S2f * h2v[4];
    const float A01 = S2f * h2v[0];
    const float A02 = S2f * h2v[3];
    const float A11 = -S6f * h2v[2] - S2f * h2v[4];
    const float A12 = S2f * h2v[1];
    const float A22 = TWOS6f * h2v[2];
    const float B00 = A00 * A00 + A01 * A01 + A02 * A02;
    const float B01 = A00 * A01 + A01 * A11 + A02 * A12;
    const float B02 = A00 * A02 + A01 * A12 + A02 * A22;
    const float B11 = A01 * A01 + A11 * A11 + A12 * A12;
    const float B12 = A01 * A02 + A11 * A12 + A12 * A22;
    const float B22 = A02 * A02 + A12 * A12 + A22 * A22;
    const float t80 = TWOS2f * B01, t81 = TWOS2f * B12;
    const float t82 = S6f * (2.f * B22 - B00 - B11);
    const float t83 = TWOS2f * B02, t84 = S2f * (B00 - B11);

    const float w15 = (v1 + v4) * h0;
    const float v6n = v6 * norm2;
    float y2r[5];
    y2r[0] = w15 * h2v[0] + v3 * t40 + v6n * t80;
    y2r[1] = w15 * h2v[1] + v3 * t41 + v6n * t81;
    y2r[2] = w15 * h2v[2] + v3 * t42 + v6n * t82;
    y2r[3] = w15 * h2v[3] + v3 * t43 + v6n * t83;
    y2r[4] = w15 * h2v[4] + v3 * t44 + v6n * t84;

#pragma unroll
    for (int off = 16; off > 0; off >>= 1) {
      y0 += __shfl_xor(y0, off, 32);
#pragma unroll
      for (int r = 0; r < 5; ++r) y2r[r] += __shfl_xor(y2r[r], off, 32);
    }
    if (u == 0) {
      sphs[nl][0] = y0;
#pragma unroll
      for (int r = 0; r < 5; ++r) sphs[nl][1 + r] = y2r[r];
    }
  }
  __syncthreads();

  // ---- phase C: cart + segment-merged atomics ----
  if (tid < 9) {
    const float QW[9][6] = {
        {ISQRT3, 0.f, 0.f, -S6f, 0.f, S2f},
        {0.f, S2f, 0.f, 0.f, 0.f, 0.f},
        {0.f, 0.f, 0.f, 0.f, S2f, 0.f},
        {0.f, S2f, 0.f, 0.f, 0.f, 0.f},
        {ISQRT3, 0.f, 0.f, -S6f, 0.f, -S2f},
        {0.f, 0.f, S2f, 0.f, 0.f, 0.f},
        {0.f, 0.f, 0.f, 0.f, S2f, 0.f},
        {0.f, 0.f, S2f, 0.f, 0.f, 0.f},
        {ISQRT3, 0.f, 0.f, TWOS6f, 0.f, 0.f}};
    const int a = tid / 3, b = tid % 3;
    const int rolled = ((a + 1) % 3) * 3 + ((b + 1) % 3);
    const float c0 = QW[tid][0], c1 = QW[tid][1], c2 = QW[tid][2];
    const float c3 = QW[tid][3], c4 = QW[tid][4], c5 = QW[tid][5];
    int cur_g = batch_s[0];
    float acc = 0.f;
#pragma unroll
    for (int q = 0; q < 8; ++q) {
      const int g = batch_s[q];
      const float val = c0 * sphs[q][0] + c1 * sphs[q][1] + c2 * sphs[q][2] +
                        c3 * sphs[q][3] + c4 * sphs[q][4] + c5 * sphs[q][5];
      if (g != cur_g) {
        atomicAdd(out + cur_g * 9 + rolled, acc);
        acc = 0.f;
        cur_g = g;
      }
      acc += val;
    }
    atomicAdd(out + cur_g * 9 + rolled, acc);
  }
}

extern "C" void kernel_launch(void* const* d_in, const int* in_sizes, int n_in,
                              void* d_out, int out_size, void* d_ws, size_t ws_size,
                              hipStream_t stream) {
  const float* x_scalar = (const float*)d_in[0];
  const float* x_sph    = (const float*)d_in[1];
  const int*   batch    = (const int*)d_in[2];
  const float* W0e      = (const float*)d_in[3];
  const float* W1o      = (const float*)d_in[4];
  const float* W2e      = (const float*)d_in[5];
  const float* Wm1      = (const float*)d_in[6];
  const float* bm1      = (const float*)d_in[7];
  const float* Wm2      = (const float*)d_in[8];
  const float* bm2      = (const float*)d_in[9];
  const float* P0       = (const float*)d_in[10];
  // P1 (d_in[11]) provably unused: C111/C221 antisymmetric vs h(x)h of same h.
  const float* P2       = (const float*)d_in[12];
  float* ws  = (float*)d_ws;
  float* out = (float*)d_out;

  if (ws_size < (size_t)WS_FLOATS * sizeof(float)) return;

  // host-side C222 normalization (pure CPU double math; = sqrt(12/7))
  double Q2[5][3][3] = {};
  const double s2d = 0.70710678118654752440, s6d = 0.40824829046386301637;
  Q2[0][0][1] = Q2[0][1][0] = s2d;
  Q2[1][1][2] = Q2[1][2][1] = s2d;
  Q2[2][0][0] = Q2[2][1][1] = -s6d; Q2[2][2][2] = 2.0 * s6d;
  Q2[3][0][2] = Q2[3][2][0] = s2d;
  Q2[4][0][0] = s2d; Q2[4][1][1] = -s2d;
  double ss = 0.0;
  for (int i = 0; i < 5; ++i)
    for (int jj = 0; jj < 5; ++jj) {
      double S[3][3];
      for (int a = 0; a < 3; ++a)
        for (int d = 0; d < 3; ++d) {
          double m1 = 0, m2 = 0;
          for (int b = 0; b < 3; ++b) {
            m1 += Q2[i][a][b] * Q2[jj][d][b];
            m2 += Q2[i][d][b] * Q2[jj][a][b];
          }
          S[a][d] = 0.5 * (m1 + m2);
        }
      double tr = (S[0][0] + S[1][1] + S[2][2]) / 3.0;
      S[0][0] -= tr; S[1][1] -= tr; S[2][2] -= tr;
      for (int kk = 0; kk < 5; ++kk) {
        double cc = 0;
        for (int a = 0; a < 3; ++a)
          for (int d = 0; d < 3; ++d) cc += Q2[kk][a][d] * S[a][d];
        ss += cc * cc;
      }
    }
  const float norm2 = (float)sqrt(5.0 / ss);

  prep_kernel<<<57, 256, 0, stream>>>(Wm2, bm2, P0, P2, ws, out);
  kv_kernel<<<1250, 256, 0, stream>>>(x_scalar, Wm1, bm1, ws);
  khd_kernel<<<2500, 256, 0, stream>>>(x_sph, batch, W0e, W1o, W2e, ws, out, norm2);
}

// Round 7
// 160.733 us; speedup vs baseline: 1.1361x; 1.0774x over previous
//
#include <hip/hip_runtime.h>
#include <math.h>

// ---------------- workspace layout (float offsets) ----------------
#define OFF_W2P 0              // [64][224]  Wm2 pre-contracted with P
#define OFF_B2P 14336          // [224]
#define OFF_V   14560          // [20000][224]
#define WS_FLOATS 4494560

#define SC_Y0 0.0180421959121758f   // (1/sqrt(32))*(1/sqrt(96))
#define SC_Y2 0.015625f             // (1/sqrt(32))*(1/sqrt(128))
#define S2f 0.70710678118654752f
#define S6f 0.40824829046386302f
#define TWOS2f 1.41421356237309505f
#define TWOS6f 0.81649658092772603f
#define ISQRT3 0.57735026918962576f
#define ISQRT5 0.44721359549995794f
#define H0SC 0.08838834764831845f   // 1/sqrt(128)
#define H1SC 0.125f                 // 1/sqrt(64)
#define H2SC 0.17677669529663689f   // 1/sqrt(32)

__device__ __constant__ int KARR[7] = {0, 1, 2, 4, 5, 6, 8};

// ---------------- prep: Wm2p, bm2p, zero out ----------------
__global__ __launch_bounds__(256) void prep_kernel(
    const float* __restrict__ Wm2, const float* __restrict__ bm2,
    const float* __restrict__ P0, const float* __restrict__ P2,
    float* __restrict__ ws, float* __restrict__ out) {
  int j = blockIdx.x * 256 + threadIdx.x;
  if (j < 2304) out[j] = 0.f;

  if (j < 14336) {
    int s = j >> 11; int rem = j & 2047; int c = rem >> 5; int u = rem & 31;
    int k = KARR[s];
    const float* P;
    float sc;
    switch (s) {
      case 0: P = P0;      sc = SC_Y0; break;
      case 1: P = P2;      sc = SC_Y2; break;
      case 2: P = P0 + 32; sc = SC_Y0; break;
      case 3: P = P2 + 32; sc = SC_Y2; break;
      case 4: P = P2 + 64; sc = SC_Y2; break;
      case 5: P = P0 + 64; sc = SC_Y0; break;
      default: P = P2 + 96; sc = SC_Y2; break;
    }
    const float4* w4 = (const float4*)(Wm2 + c * 9216 + k * 1024 + u * 32);
    const float4* p4 = (const float4*)P;
    float acc = 0.f;
#pragma unroll
    for (int q = 0; q < 8; ++q) {
      float4 a = w4[q], b = p4[q];
      acc += a.x * b.x + a.y * b.y + a.z * b.z + a.w * b.w;
    }
    ws[OFF_W2P + c * 224 + s * 32 + u] = acc * sc;
  } else if (j < 14560) {
    int i = j - 14336; int s = i >> 5; int u = i & 31; int k = KARR[s];
    const float* P;
    float sc;
    switch (s) {
      case 0: P = P0;      sc = SC_Y0; break;
      case 1: P = P2;      sc = SC_Y2; break;
      case 2: P = P0 + 32; sc = SC_Y0; break;
      case 3: P = P2 + 32; sc = SC_Y2; break;
      case 4: P = P2 + 64; sc = SC_Y2; break;
      case 5: P = P0 + 64; sc = SC_Y0; break;
      default: P = P2 + 96; sc = SC_Y2; break;
    }
    const float* b = bm2 + k * 1024 + u * 32;
    float acc = 0.f;
#pragma unroll
    for (int w = 0; w < 32; ++w) acc += b[w] * P[w];
    ws[OFF_B2P + s * 32 + u] = acc * sc;
  }
}

// ---------------- kv: 32 nodes/block, hidden 4nx4c, V 8nx8o ----------------
// LDS: xs[32][132] (16896 B) + hiT[64][36] (9216 B) = 26112 B
__global__ __launch_bounds__(256) void kv_kernel(
    const float* __restrict__ xs_g, const float* __restrict__ Wm1,
    const float* __restrict__ bm1, float* __restrict__ ws) {
  __shared__ __align__(16) float xs[32][132];
  __shared__ __align__(16) float hiT[64][36];
  const int tid = threadIdx.x;
  const int n0 = blockIdx.x * 32;   // 625 * 32 == 20000

  for (int idx = tid; idx < 1024; idx += 256) {
    const int row = idx >> 5, c4 = idx & 31;
    *(float4*)&xs[row][c4 * 4] = *(const float4*)(xs_g + (n0 + row) * 128 + c4 * 4);
  }
  __syncthreads();

  if (tid < 128) {  // hidden: 4n x 4c per thread (8 ng x 16 cg)
    const int cg = tid & 15, ng = tid >> 4;
    const int c0 = cg * 4, nl = ng * 4;
    float acc[4][4] = {{0.f}};
#pragma unroll 2
    for (int mq = 0; mq < 32; ++mq) {
      float4 xv[4], wv[4];
#pragma unroll
      for (int i = 0; i < 4; ++i) xv[i] = *(float4*)&xs[nl + i][mq * 4];
#pragma unroll
      for (int r = 0; r < 4; ++r) wv[r] = *(const float4*)(Wm1 + (mq * 4 + r) * 64 + c0);
#pragma unroll
      for (int r = 0; r < 4; ++r) {
        const float4 w = wv[r];
#pragma unroll
        for (int i = 0; i < 4; ++i) {
          const float xr = (r == 0) ? xv[i].x : (r == 1) ? xv[i].y : (r == 2) ? xv[i].z : xv[i].w;
          acc[i][0] += xr * w.x; acc[i][1] += xr * w.y;
          acc[i][2] += xr * w.z; acc[i][3] += xr * w.w;
        }
      }
    }
    const float4 bb = *(const float4*)(bm1 + c0);
    const float bv[4] = {bb.x, bb.y, bb.z, bb.w};
#pragma unroll
    for (int i = 0; i < 4; ++i)
#pragma unroll
      for (int jj = 0; jj < 4; ++jj) {
        float z = acc[i][jj] + bv[jj];
        hiT[c0 + jj][nl + i] = z / (1.f + __expf(-z));
      }
  }
  __syncthreads();

  if (tid < 112) {  // V: 8n x 8o per thread (28 og x 4 ng)
    const int og = tid >> 2, ng = tid & 3;
    const int o0 = og * 8, nl = ng * 8;
    const float4 blo = *(const float4*)(ws + OFF_B2P + o0);
    const float4 bhi = *(const float4*)(ws + OFF_B2P + o0 + 4);
    float acc[8][8];
#pragma unroll
    for (int i = 0; i < 8; ++i) {
      acc[i][0] = blo.x; acc[i][1] = blo.y; acc[i][2] = blo.z; acc[i][3] = blo.w;
      acc[i][4] = bhi.x; acc[i][5] = bhi.y; acc[i][6] = bhi.z; acc[i][7] = bhi.w;
    }
#pragma unroll 2
    for (int c = 0; c < 64; ++c) {
      const float4 ha = *(float4*)&hiT[c][nl];
      const float4 hb = *(float4*)&hiT[c][nl + 4];
      const float4 wlo = *(const float4*)(ws + OFF_W2P + c * 224 + o0);
      const float4 whi = *(const float4*)(ws + OFF_W2P + c * 224 + o0 + 4);
      const float hv[8] = {ha.x, ha.y, ha.z, ha.w, hb.x, hb.y, hb.z, hb.w};
      const float wv[8] = {wlo.x, wlo.y, wlo.z, wlo.w, whi.x, whi.y, whi.z, whi.w};
#pragma unroll
      for (int i = 0; i < 8; ++i)
#pragma unroll
        for (int jj = 0; jj < 8; ++jj) acc[i][jj] += hv[i] * wv[jj];
    }
#pragma unroll
    for (int i = 0; i < 8; ++i) {
      const int n_g = n0 + nl + i;
      float4 a = {acc[i][0], acc[i][1], acc[i][2], acc[i][3]};
      float4 b = {acc[i][4], acc[i][5], acc[i][6], acc[i][7]};
      *(float4*)(ws + OFF_V + n_g * 224 + o0) = a;
      *(float4*)(ws + OFF_V + n_g * 224 + o0 + 4) = b;
    }
  }
}

// ---------------- khd: 16 nodes/block, weights reused across 2 halves ----------------
// LDS (bytes): xp[16][484] @0 (30976), h0s[16][36] @30976 (2304),
//   h1s[16][3][36] @33280 (6912), h2s[16][5][36] @40192 (11520),
//   sphs[16][6] @51712 (384), batch_s[16] @52096 (64) -> 52160 B, 3 blocks/CU
__global__ __launch_bounds__(256) void khd_kernel(
    const float* __restrict__ xsph, const int* __restrict__ batch,
    const float* __restrict__ W0e, const float* __restrict__ W1o,
    const float* __restrict__ W2e,
    const float* __restrict__ ws, float* __restrict__ out, const float norm2) {
  __shared__ __align__(16) char smem[52160];
  float (*xp)[484]    = (float (*)[484])smem;
  float (*h0s)[36]    = (float (*)[36])(smem + 30976);
  float (*h1s)[3][36] = (float (*)[3][36])(smem + 33280);
  float (*h2s)[5][36] = (float (*)[5][36])(smem + 40192);
  float (*sphs)[6]    = (float (*)[6])(smem + 51712);
  int* batch_s        = (int*)(smem + 52096);

  const int tid = threadIdx.x;
  const int n0 = blockIdx.x * 16;   // 1250 * 16 == 20000

  // V into registers up-front (coalesced b32, both halves)
  const int nl8 = tid >> 5, u = tid & 31;
  float vreg[2][7];
  {
    const float* Vg0 = ws + OFF_V + (size_t)(n0 + nl8) * 224 + u;
    const float* Vg1 = Vg0 + 8 * 224;
#pragma unroll
    for (int s = 0; s < 7; ++s) {
      vreg[0][s] = Vg0[s * 32];
      vreg[1][s] = Vg1[s * 32];
    }
  }
  if (tid < 16) batch_s[tid] = batch[n0 + tid];

  // stage x_sph tile coalesced (1920 float4)
  for (int idx = tid; idx < 1920; idx += 256) {
    const int row = idx / 120, c4 = idx % 120;
    *(float4*)&xp[row][c4 * 4] =
        *(const float4*)(xsph + (size_t)(n0 + row) * 480 + c4 * 4);
  }
  __syncthreads();

  // ---- phase A: wave-split h-projections; W loaded once, applied to both halves ----
  if (tid < 64) {
    // wave 0: h1 j=0,1
    const int n8 = tid & 7, u0 = ((tid >> 3) & 7) * 4;
    float acc[2][2][4] = {{{0.f}}};
#pragma unroll 2
    for (int mq = 0; mq < 16; ++mq) {
      float wv[4][4];
#pragma unroll
      for (int mm = 0; mm < 4; ++mm) {
        const float4 w = *(const float4*)(W1o + (mq * 4 + mm) * 32 + u0);
        wv[mm][0] = w.x; wv[mm][1] = w.y; wv[mm][2] = w.z; wv[mm][3] = w.w;
      }
#pragma unroll
      for (int half = 0; half < 2; ++half) {
        const int n = half * 8 + n8;
        const float4 a0 = *(float4*)&xp[n][128 + mq * 12];
        const float4 a1 = *(float4*)&xp[n][128 + mq * 12 + 4];
        const float4 a2 = *(float4*)&xp[n][128 + mq * 12 + 8];
        const float xa[12] = {a0.x, a0.y, a0.z, a0.w, a1.x, a1.y, a1.z, a1.w,
                              a2.x, a2.y, a2.z, a2.w};
#pragma unroll
        for (int mm = 0; mm < 4; ++mm)
#pragma unroll
          for (int j = 0; j < 2; ++j) {
            const float xr = xa[mm * 3 + j];
#pragma unroll
            for (int jj = 0; jj < 4; ++jj) acc[half][j][jj] += xr * wv[mm][jj];
          }
      }
    }
#pragma unroll
    for (int half = 0; half < 2; ++half)
#pragma unroll
      for (int j = 0; j < 2; ++j) {
        float4 a = {acc[half][j][0] * H1SC, acc[half][j][1] * H1SC,
                    acc[half][j][2] * H1SC, acc[half][j][3] * H1SC};
        *(float4*)&h1s[half * 8 + n8][j][u0] = a;
      }
  } else if (tid < 128) {
    // wave 1: h2 j=1..4
    const int t = tid - 64;
    const int n8 = t & 7, u0 = ((t >> 3) & 7) * 4;
    float acc[2][4][4] = {{{0.f}}};
#pragma unroll 1
    for (int mq = 0; mq < 8; ++mq) {
      float wv[4][4];
#pragma unroll
      for (int mm = 0; mm < 4; ++mm) {
        const float4 w = *(const float4*)(W2e + (mq * 4 + mm) * 32 + u0);
        wv[mm][0] = w.x; wv[mm][1] = w.y; wv[mm][2] = w.z; wv[mm][3] = w.w;
      }
#pragma unroll
      for (int half = 0; half < 2; ++half) {
        const int n = half * 8 + n8;
        const float4 a0 = *(float4*)&xp[n][320 + mq * 20];
        const float4 a1 = *(float4*)&xp[n][320 + mq * 20 + 4];
        const float4 a2 = *(float4*)&xp[n][320 + mq * 20 + 8];
        const float4 a3 = *(float4*)&xp[n][320 + mq * 20 + 12];
        const float4 a4 = *(float4*)&xp[n][320 + mq * 20 + 16];
        const float xa[20] = {a0.x, a0.y, a0.z, a0.w, a1.x, a1.y, a1.z, a1.w,
                              a2.x, a2.y, a2.z, a2.w, a3.x, a3.y, a3.z, a3.w,
                              a4.x, a4.y, a4.z, a4.w};
#pragma unroll
        for (int mm = 0; mm < 4; ++mm)
#pragma unroll
          for (int j = 1; j < 5; ++j) {
            const float xr = xa[mm * 5 + j];
#pragma unroll
            for (int jj = 0; jj < 4; ++jj) acc[half][j - 1][jj] += xr * wv[mm][jj];
          }
      }
    }
#pragma unroll
    for (int half = 0; half < 2; ++half)
#pragma unroll
      for (int j = 1; j < 5; ++j) {
        float4 a = {acc[half][j - 1][0] * H2SC, acc[half][j - 1][1] * H2SC,
                    acc[half][j - 1][2] * H2SC, acc[half][j - 1][3] * H2SC};
        *(float4*)&h2s[half * 8 + n8][j][u0] = a;
      }
  } else if (tid < 192) {
    // wave 2: h0
    const int t = tid - 128;
    const int n8 = t & 7, u0 = ((t >> 3) & 7) * 4;
    float acc[2][4] = {{0.f}};
#pragma unroll 2
    for (int mq = 0; mq < 32; ++mq) {
      float wv[4][4];
#pragma unroll
      for (int r = 0; r < 4; ++r) {
        const float4 w = *(const float4*)(W0e + (mq * 4 + r) * 32 + u0);
        wv[r][0] = w.x; wv[r][1] = w.y; wv[r][2] = w.z; wv[r][3] = w.w;
      }
#pragma unroll
      for (int half = 0; half < 2; ++half) {
        const int n = half * 8 + n8;
        const float4 xv = *(float4*)&xp[n][mq * 4];
        const float xa[4] = {xv.x, xv.y, xv.z, xv.w};
#pragma unroll
        for (int r = 0; r < 4; ++r) {
          const float xr = xa[r];
#pragma unroll
          for (int jj = 0; jj < 4; ++jj) acc[half][jj] += xr * wv[r][jj];
        }
      }
    }
#pragma unroll
    for (int half = 0; half < 2; ++half) {
      float4 a = {acc[half][0] * H0SC, acc[half][1] * H0SC,
                  acc[half][2] * H0SC, acc[half][3] * H0SC};
      *(float4*)&h0s[half * 8 + n8][u0] = a;
    }
  } else {
    // wave 3: h1 j=2 and h2 j=0
    const int t = tid - 192;
    const int n8 = t & 7, u0 = ((t >> 3) & 7) * 4;
    float acc1[2][4] = {{0.f}};
#pragma unroll 2
    for (int mq = 0; mq < 16; ++mq) {
      float wv[4][4];
#pragma unroll
      for (int mm = 0; mm < 4; ++mm) {
        const float4 w = *(const float4*)(W1o + (mq * 4 + mm) * 32 + u0);
        wv[mm][0] = w.x; wv[mm][1] = w.y; wv[mm][2] = w.z; wv[mm][3] = w.w;
      }
#pragma unroll
      for (int half = 0; half < 2; ++half) {
        const int n = half * 8 + n8;
        const float4 a0 = *(float4*)&xp[n][128 + mq * 12];
        const float4 a1 = *(float4*)&xp[n][128 + mq * 12 + 4];
        const float4 a2 = *(float4*)&xp[n][128 + mq * 12 + 8];
        const float xa[12] = {a0.x, a0.y, a0.z, a0.w, a1.x, a1.y, a1.z, a1.w,
                              a2.x, a2.y, a2.z, a2.w};
#pragma unroll
        for (int mm = 0; mm < 4; ++mm) {
          const float xr = xa[mm * 3 + 2];
#pragma unroll
          for (int jj = 0; jj < 4; ++jj) acc1[half][jj] += xr * wv[mm][jj];
        }
      }
    }
#pragma unroll
    for (int half = 0; half < 2; ++half) {
      float4 a = {acc1[half][0] * H1SC, acc1[half][1] * H1SC,
                  acc1[half][2] * H1SC, acc1[half][3] * H1SC};
      *(float4*)&h1s[half * 8 + n8][2][u0] = a;
    }
    float acc2[2][4] = {{0.f}};
#pragma unroll 1
    for (int mq = 0; mq < 8; ++mq) {
      float wv[4][4];
#pragma unroll
      for (int mm = 0; mm < 4; ++mm) {
        const float4 w = *(const float4*)(W2e + (mq * 4 + mm) * 32 + u0);
        wv[mm][0] = w.x; wv[mm][1] = w.y; wv[mm][2] = w.z; wv[mm][3] = w.w;
      }
#pragma unroll
      for (int half = 0; half < 2; ++half) {
        const int n = half * 8 + n8;
        const float4 a0 = *(float4*)&xp[n][320 + mq * 20];
        const float4 a1 = *(float4*)&xp[n][320 + mq * 20 + 4];
        const float4 a2 = *(float4*)&xp[n][320 + mq * 20 + 8];
        const float4 a3 = *(float4*)&xp[n][320 + mq * 20 + 12];
        const float4 a4 = *(float4*)&xp[n][320 + mq * 20 + 16];
        const float xa[20] = {a0.x, a0.y, a0.z, a0.w, a1.x, a1.y, a1.z, a1.w,
                              a2.x, a2.y, a2.z, a2.w, a3.x, a3.y, a3.z, a3.w,
                              a4.x, a4.y, a4.z, a4.w};
#pragma unroll
        for (int mm = 0; mm < 4; ++mm) {
          const float xr = xa[mm * 5 + 0];
#pragma unroll
          for (int jj = 0; jj < 4; ++jj) acc2[half][jj] += xr * wv[mm][jj];
        }
      }
    }
#pragma unroll
    for (int half = 0; half < 2; ++half) {
      float4 a = {acc2[half][0] * H2SC, acc2[half][1] * H2SC,
                  acc2[half][2] * H2SC, acc2[half][3] * H2SC};
      *(float4*)&h2s[half * 8 + n8][0][u0] = a;
    }
  }
  __syncthreads();

  // ---- phase B: per-(n,u) path math, both halves (h from LDS, V in registers) ----
#pragma unroll 2
  for (int half = 0; half < 2; ++half) {
    const int n = half * 8 + nl8;
    const float h0 = h0s[n][u];
    const float h1a = h1s[n][0][u], h1b = h1s[n][1][u], h1c = h1s[n][2][u];
    float h2v[5];
#pragma unroll
    for (int j = 0; j < 5; ++j) h2v[j] = h2s[n][j][u];
    const float v0 = vreg[half][0], v1 = vreg[half][1], v2 = vreg[half][2],
                v3 = vreg[half][3], v4 = vreg[half][4], v5 = vreg[half][5],
                v6 = vreg[half][6];

    const float d11 = h1a * h1a + h1b * h1b + h1c * h1c;
    const float d22 = h2v[0] * h2v[0] + h2v[1] * h2v[1] + h2v[2] * h2v[2] +
                      h2v[3] * h2v[3] + h2v[4] * h2v[4];
    float y0 = v0 * h0 * h0 + v2 * d11 * ISQRT3 + v5 * d22 * ISQRT5;

    const float o00 = h1a * h1a, o01 = h1a * h1b, o02 = h1a * h1c;
    const float o11 = h1b * h1b, o12 = h1b * h1c, o22 = h1c * h1c;
    const float t40 = TWOS2f * o01, t41 = TWOS2f * o12;
    const float t42 = S6f * (2.f * o22 - o00 - o11);
    const float t43 = TWOS2f * o02, t44 = S2f * (o00 - o11);

    const float A00 = -S6f * h2v[2] + S2f * h2v[4];
    const float A01 = S2f * h2v[0];
    const float A02 = S2f * h2v[3];
    const float A11 = -S6f * h2v[2] - S2f * h2v[4];
    const float A12 = S2f * h2v[1];
    const float A22 = TWOS6f * h2v[2];
    const float B00 = A00 * A00 + A01 * A01 + A02 * A02;
    const float B01 = A00 * A01 + A01 * A11 + A02 * A12;
    const float B02 = A00 * A02 + A01 * A12 + A02 * A22;
    const float B11 = A01 * A01 + A11 * A11 + A12 * A12;
    const float B12 = A01 * A02 + A11 * A12 + A12 * A22;
    const float B22 = A02 * A02 + A12 * A12 + A22 * A22;
    const float t80 = TWOS2f * B01, t81 = TWOS2f * B12;
    const float t82 = S6f * (2.f * B22 - B00 - B11);
    const float t83 = TWOS2f * B02, t84 = S2f * (B00 - B11);

    const float w15 = (v1 + v4) * h0;
    const float v6n = v6 * norm2;
    float y2r[5];
    y2r[0] = w15 * h2v[0] + v3 * t40 + v6n * t80;
    y2r[1] = w15 * h2v[1] + v3 * t41 + v6n * t81;
    y2r[2] = w15 * h2v[2] + v3 * t42 + v6n * t82;
    y2r[3] = w15 * h2v[3] + v3 * t43 + v6n * t83;
    y2r[4] = w15 * h2v[4] + v3 * t44 + v6n * t84;

#pragma unroll
    for (int off = 16; off > 0; off >>= 1) {
      y0 += __shfl_xor(y0, off, 32);
#pragma unroll
      for (int r = 0; r < 5; ++r) y2r[r] += __shfl_xor(y2r[r], off, 32);
    }
    if (u == 0) {
      sphs[n][0] = y0;
#pragma unroll
      for (int r = 0; r < 5; ++r) sphs[n][1 + r] = y2r[r];
    }
  }
  __syncthreads();

  // ---- phase C: cart + segment-merged atomics ----
  if (tid < 9) {
    const float QW[9][6] = {
        {ISQRT3, 0.f, 0.f, -S6f, 0.f, S2f},
        {0.f, S2f, 0.f, 0.f, 0.f, 0.f},
        {0.f, 0.f, 0.f, 0.f, S2f, 0.f},
        {0.f, S2f, 0.f, 0.f, 0.f, 0.f},
        {ISQRT3, 0.f, 0.f, -S6f, 0.f, -S2f},
        {0.f, 0.f, S2f, 0.f, 0.f, 0.f},
        {0.f, 0.f, 0.f, 0.f, S2f, 0.f},
        {0.f, 0.f, S2f, 0.f, 0.f, 0.f},
        {ISQRT3, 0.f, 0.f, TWOS6f, 0.f, 0.f}};
    const int a = tid / 3, b = tid % 3;
    const int rolled = ((a + 1) % 3) * 3 + ((b + 1) % 3);
    const float c0 = QW[tid][0], c1 = QW[tid][1], c2 = QW[tid][2];
    const float c3 = QW[tid][3], c4 = QW[tid][4], c5 = QW[tid][5];
    int cur_g = batch_s[0];
    float acc = 0.f;
#pragma unroll 4
    for (int q = 0; q < 16; ++q) {
      const int g = batch_s[q];
      const float val = c0 * sphs[q][0] + c1 * sphs[q][1] + c2 * sphs[q][2] +
                        c3 * sphs[q][3] + c4 * sphs[q][4] + c5 * sphs[q][5];
      if (g != cur_g) {
        atomicAdd(out + cur_g * 9 + rolled, acc);
        acc = 0.f;
        cur_g = g;
      }
      acc += val;
    }
    atomicAdd(out + cur_g * 9 + rolled, acc);
  }
}

extern "C" void kernel_launch(void* const* d_in, const int* in_sizes, int n_in,
                              void* d_out, int out_size, void* d_ws, size_t ws_size,
                              hipStream_t stream) {
  const float* x_scalar = (const float*)d_in[0];
  const float* x_sph    = (const float*)d_in[1];
  const int*   batch    = (const int*)d_in[2];
  const float* W0e      = (const float*)d_in[3];
  const float* W1o      = (const float*)d_in[4];
  const float* W2e      = (const float*)d_in[5];
  const float* Wm1      = (const float*)d_in[6];
  const float* bm1      = (const float*)d_in[7];
  const float* Wm2      = (const float*)d_in[8];
  const float* bm2      = (const float*)d_in[9];
  const float* P0       = (const float*)d_in[10];
  // P1 (d_in[11]) provably unused: C111/C221 antisymmetric vs h(x)h of same h.
  const float* P2       = (const float*)d_in[12];
  float* ws  = (float*)d_ws;
  float* out = (float*)d_out;

  if (ws_size < (size_t)WS_FLOATS * sizeof(float)) return;

  // host-side C222 normalization (pure CPU double math; = sqrt(12/7))
  double Q2[5][3][3] = {};
  const double s2d = 0.70710678118654752440, s6d = 0.40824829046386301637;
  Q2[0][0][1] = Q2[0][1][0] = s2d;
  Q2[1][1][2] = Q2[1][2][1] = s2d;
  Q2[2][0][0] = Q2[2][1][1] = -s6d; Q2[2][2][2] = 2.0 * s6d;
  Q2[3][0][2] = Q2[3][2][0] = s2d;
  Q2[4][0][0] = s2d; Q2[4][1][1] = -s2d;
  double ss = 0.0;
  for (int i = 0; i < 5; ++i)
    for (int jj = 0; jj < 5; ++jj) {
      double S[3][3];
      for (int a = 0; a < 3; ++a)
        for (int d = 0; d < 3; ++d) {
          double m1 = 0, m2 = 0;
          for (int b = 0; b < 3; ++b) {
            m1 += Q2[i][a][b] * Q2[jj][d][b];
            m2 += Q2[i][d][b] * Q2[jj][a][b];
          }
          S[a][d] = 0.5 * (m1 + m2);
        }
      double tr = (S[0][0] + S[1][1] + S[2][2]) / 3.0;
      S[0][0] -= tr; S[1][1] -= tr; S[2][2] -= tr;
      for (int kk = 0; kk < 5; ++kk) {
        double cc = 0;
        for (int a = 0; a < 3; ++a)
          for (int d = 0; d < 3; ++d) cc += Q2[kk][a][d] * S[a][d];
        ss += cc * cc;
      }
    }
  const float norm2 = (float)sqrt(5.0 / ss);

  prep_kernel<<<57, 256, 0, stream>>>(Wm2, bm2, P0, P2, ws, out);
  kv_kernel<<<625, 256, 0, stream>>>(x_scalar, Wm1, bm1, ws);
  khd_kernel<<<1250, 256, 0, stream>>>(x_sph, batch, W0e, W1o, W2e, ws, out, norm2);
}